// Round 1
// baseline (200.706 us; speedup 1.0000x reference)
//
#include <hip/hip_runtime.h>
#include <cstdint>
#include <cstddef>

#define LNUM 8
#define NTOK 8192
#define HDIM 768
#define IDIM 1536

typedef __bf16 bf16x8 __attribute__((ext_vector_type(8)));
typedef __bf16 bf16x4 __attribute__((ext_vector_type(4)));
typedef float f32x4 __attribute__((ext_vector_type(4)));

__device__ __forceinline__ void gload16(void* lds, const void* gsrc) {
  __builtin_amdgcn_global_load_lds(
      (const __attribute__((address_space(1))) void*)gsrc,
      (__attribute__((address_space(3))) void*)lds, 16, 0, 0);
}

// ---------------- grouping kernels ----------------
// meta layout (ints): [0..7]=counts, [8..15]=cursor, [16..24]=offs, [25..33]=tileOffs
__global__ void hist_kernel(const int* __restrict__ lid, int* __restrict__ meta) {
  __shared__ int c[LNUM];
  if (threadIdx.x < LNUM) c[threadIdx.x] = 0;
  __syncthreads();
  int i = blockIdx.x * blockDim.x + threadIdx.x;
  atomicAdd(&c[lid[i]], 1);
  __syncthreads();
  if (threadIdx.x < LNUM) atomicAdd(&meta[threadIdx.x], c[threadIdx.x]);
}

__global__ void scan_kernel(int* __restrict__ meta) {
  if (threadIdx.x == 0) {
    int o = 0, t = 0;
    for (int e = 0; e < LNUM; ++e) {
      meta[16 + e] = o;
      meta[25 + e] = t;
      o += meta[e];
      t += (meta[e] + 127) >> 7;
    }
    meta[16 + LNUM] = o;
    meta[25 + LNUM] = t;
  }
}

__global__ void scatter_kernel(const int* __restrict__ lid, int* __restrict__ meta,
                               int* __restrict__ perm) {
  int i = blockIdx.x * blockDim.x + threadIdx.x;
  int e = lid[i];
  int pos = atomicAdd(&meta[8 + e], 1);
  perm[meta[16 + e] + pos] = i;
}

// ---------------- conversion kernels ----------------
__global__ void conv_z_kernel(const float4* __restrict__ z, bf16x4* __restrict__ zb) {
  int i = blockIdx.x * 256 + threadIdx.x;
  float4 v = z[i];
  bf16x4 o;
  o[0] = (__bf16)v.x; o[1] = (__bf16)v.y; o[2] = (__bf16)v.z; o[3] = (__bf16)v.w;
  zb[i] = o;
}

// in: [L][R][C] f32, out: [L][C][R] bf16 (transpose + convert)
__global__ void transpose_cvt_kernel(const float* __restrict__ in, __bf16* __restrict__ out,
                                     int R, int C) {
  __shared__ float tile[32][33];
  int e = blockIdx.z;
  int c0 = blockIdx.x * 32, r0 = blockIdx.y * 32;
  const float* src = in + (size_t)e * R * C;
  __bf16* dst = out + (size_t)e * R * C;
  int tx = threadIdx.x, ty = threadIdx.y;
  #pragma unroll
  for (int j = 0; j < 32; j += 8)
    tile[ty + j][tx] = src[(size_t)(r0 + ty + j) * C + c0 + tx];
  __syncthreads();
  #pragma unroll
  for (int j = 0; j < 32; j += 8)
    dst[(size_t)(c0 + ty + j) * R + r0 + tx] = (__bf16)tile[tx][ty + j];
}

// ---------------- grouped GEMM 1: act = gelu(zb[perm] @ w1t^T + b1) ----------------
// A: gathered rows of zb [NTOK][HDIM]; B: w1t [L][IDIM][HDIM] (n-major, k-contig)
__global__ __launch_bounds__(256) void gemm1_kernel(
    const __bf16* __restrict__ zb, const __bf16* __restrict__ w1t,
    const float* __restrict__ b1, const int* __restrict__ meta,
    const int* __restrict__ perm, __bf16* __restrict__ act) {
  __shared__ __bf16 As[128 * 64];
  __shared__ __bf16 Bs[128 * 64];
  const int* offs = meta + 16;
  const int* tiles = meta + 25;
  int t = blockIdx.y;
  if (t >= tiles[LNUM]) return;
  int e = 0;
  #pragma unroll
  for (int q = 0; q < LNUM - 1; ++q)
    if (t >= tiles[e + 1]) ++e;
  int mtile = t - tiles[e];
  int row0 = offs[e] + (mtile << 7);
  int cntRem = offs[e + 1] - row0;
  if (cntRem > 128) cntRem = 128;
  int n0 = blockIdx.x << 7;
  int tid = threadIdx.x, lane = tid & 63, wv = tid >> 6;
  int wr = wv >> 1, wc = wv & 1;

  const __bf16* srcA[4];
  const __bf16* srcB[4];
  #pragma unroll
  for (int i = 0; i < 4; ++i) {
    int row = ((wv * 4 + i) << 3) + (lane >> 3);
    int rA = row < cntRem ? row : cntRem - 1;
    int tok = perm[row0 + rA];
    srcA[i] = zb + (size_t)tok * HDIM + ((lane & 7) << 3);
    srcB[i] = w1t + ((size_t)e * IDIM + n0 + row) * HDIM + ((lane & 7) << 3);
  }

  f32x4 acc[4][4] = {};

  for (int kk = 0; kk < HDIM / 64; ++kk) {
    #pragma unroll
    for (int i = 0; i < 4; ++i) {
      gload16((char*)As + ((wv * 4 + i) << 10), srcA[i] + kk * 64);
      gload16((char*)Bs + ((wv * 4 + i) << 10), srcB[i] + kk * 64);
    }
    __syncthreads();
    #pragma unroll
    for (int k2 = 0; k2 < 2; ++k2) {
      bf16x8 a[4], b[4];
      #pragma unroll
      for (int mi = 0; mi < 4; ++mi)
        a[mi] = *(const bf16x8*)&As[((wr * 64 + mi * 16 + (lane & 15)) << 6) + k2 * 32 + ((lane >> 4) << 3)];
      #pragma unroll
      for (int ni = 0; ni < 4; ++ni)
        b[ni] = *(const bf16x8*)&Bs[((wc * 64 + ni * 16 + (lane & 15)) << 6) + k2 * 32 + ((lane >> 4) << 3)];
      #pragma unroll
      for (int mi = 0; mi < 4; ++mi)
        #pragma unroll
        for (int ni = 0; ni < 4; ++ni)
          acc[mi][ni] = __builtin_amdgcn_mfma_f32_16x16x32_bf16(a[mi], b[ni], acc[mi][ni], 0, 0, 0);
    }
    __syncthreads();
  }

  #pragma unroll
  for (int mi = 0; mi < 4; ++mi) {
    int gr0 = wr * 64 + mi * 16 + ((lane >> 4) << 2);
    #pragma unroll
    for (int r = 0; r < 4; ++r) {
      int g = gr0 + r;
      if (g < cntRem) {
        size_t p = (size_t)(row0 + g);
        #pragma unroll
        for (int ni = 0; ni < 4; ++ni) {
          int col = n0 + wc * 64 + ni * 16 + (lane & 15);
          float x = acc[mi][ni][r] + b1[e * IDIM + col];
          float ge = 0.5f * x * (1.0f + erff(x * 0.70710678118654752f));
          act[p * IDIM + col] = (__bf16)ge;
        }
      }
    }
  }
}

// ---------------- grouped GEMM 2: out[tok] = z[tok] + act @ w2t^T + b2 ----------------
__global__ __launch_bounds__(256) void gemm2_kernel(
    const __bf16* __restrict__ act, const __bf16* __restrict__ w2t,
    const float* __restrict__ b2, const float* __restrict__ z,
    const int* __restrict__ meta, const int* __restrict__ perm,
    float* __restrict__ out) {
  __shared__ __bf16 As[128 * 64];
  __shared__ __bf16 Bs[128 * 64];
  const int* offs = meta + 16;
  const int* tiles = meta + 25;
  int t = blockIdx.y;
  if (t >= tiles[LNUM]) return;
  int e = 0;
  #pragma unroll
  for (int q = 0; q < LNUM - 1; ++q)
    if (t >= tiles[e + 1]) ++e;
  int mtile = t - tiles[e];
  int row0 = offs[e] + (mtile << 7);
  int cntRem = offs[e + 1] - row0;
  if (cntRem > 128) cntRem = 128;
  int n0 = blockIdx.x << 7;
  int tid = threadIdx.x, lane = tid & 63, wv = tid >> 6;
  int wr = wv >> 1, wc = wv & 1;

  const __bf16* srcA[4];
  const __bf16* srcB[4];
  #pragma unroll
  for (int i = 0; i < 4; ++i) {
    int row = ((wv * 4 + i) << 3) + (lane >> 3);
    int rA = row < cntRem ? row : cntRem - 1;
    srcA[i] = act + (size_t)(row0 + rA) * IDIM + ((lane & 7) << 3);
    srcB[i] = w2t + ((size_t)e * HDIM + n0 + row) * IDIM + ((lane & 7) << 3);
  }

  f32x4 acc[4][4] = {};

  for (int kk = 0; kk < IDIM / 64; ++kk) {
    #pragma unroll
    for (int i = 0; i < 4; ++i) {
      gload16((char*)As + ((wv * 4 + i) << 10), srcA[i] + kk * 64);
      gload16((char*)Bs + ((wv * 4 + i) << 10), srcB[i] + kk * 64);
    }
    __syncthreads();
    #pragma unroll
    for (int k2 = 0; k2 < 2; ++k2) {
      bf16x8 a[4], b[4];
      #pragma unroll
      for (int mi = 0; mi < 4; ++mi)
        a[mi] = *(const bf16x8*)&As[((wr * 64 + mi * 16 + (lane & 15)) << 6) + k2 * 32 + ((lane >> 4) << 3)];
      #pragma unroll
      for (int ni = 0; ni < 4; ++ni)
        b[ni] = *(const bf16x8*)&Bs[((wc * 64 + ni * 16 + (lane & 15)) << 6) + k2 * 32 + ((lane >> 4) << 3)];
      #pragma unroll
      for (int mi = 0; mi < 4; ++mi)
        #pragma unroll
        for (int ni = 0; ni < 4; ++ni)
          acc[mi][ni] = __builtin_amdgcn_mfma_f32_16x16x32_bf16(a[mi], b[ni], acc[mi][ni], 0, 0, 0);
    }
    __syncthreads();
  }

  #pragma unroll
  for (int mi = 0; mi < 4; ++mi) {
    int gr0 = wr * 64 + mi * 16 + ((lane >> 4) << 2);
    #pragma unroll
    for (int r = 0; r < 4; ++r) {
      int g = gr0 + r;
      if (g < cntRem) {
        int p = row0 + g;
        int tok = perm[p];
        #pragma unroll
        for (int ni = 0; ni < 4; ++ni) {
          int col = n0 + wc * 64 + ni * 16 + (lane & 15);
          out[(size_t)tok * HDIM + col] =
              z[(size_t)tok * HDIM + col] + acc[mi][ni][r] + b2[e * HDIM + col];
        }
      }
    }
  }
}

extern "C" void kernel_launch(void* const* d_in, const int* in_sizes, int n_in,
                              void* d_out, int out_size, void* d_ws, size_t ws_size,
                              hipStream_t stream) {
  const float* z  = (const float*)d_in[0];
  const int*   lid = (const int*)d_in[1];
  const float* w1 = (const float*)d_in[2];
  const float* b1 = (const float*)d_in[3];
  const float* w2 = (const float*)d_in[4];
  const float* b2 = (const float*)d_in[5];
  float* out = (float*)d_out;
  char* ws = (char*)d_ws;

  int* meta = (int*)ws;             // 34 ints
  int* perm = (int*)(ws + 256);     // NTOK ints
  __bf16* zb  = (__bf16*)(ws + 33280);
  __bf16* w1t = zb + (size_t)NTOK * HDIM;
  __bf16* w2t = w1t + (size_t)LNUM * HDIM * IDIM;
  __bf16* act = w2t + (size_t)LNUM * HDIM * IDIM;

  hipMemsetAsync(meta, 0, 64, stream);  // counts + cursors
  hist_kernel<<<NTOK / 256, 256, 0, stream>>>(lid, meta);
  scan_kernel<<<1, 64, 0, stream>>>(meta);
  scatter_kernel<<<NTOK / 256, 256, 0, stream>>>(lid, meta, perm);
  conv_z_kernel<<<(NTOK * HDIM / 4) / 256, 256, 0, stream>>>((const float4*)z, (bf16x4*)zb);
  transpose_cvt_kernel<<<dim3(IDIM / 32, HDIM / 32, LNUM), dim3(32, 8), 0, stream>>>(w1, w1t, HDIM, IDIM);
  transpose_cvt_kernel<<<dim3(HDIM / 32, IDIM / 32, LNUM), dim3(32, 8), 0, stream>>>(w2, w2t, IDIM, HDIM);
  gemm1_kernel<<<dim3(IDIM / 128, 72), 256, 0, stream>>>(zb, w1t, b1, meta, perm, act);
  gemm2_kernel<<<dim3(HDIM / 128, 72), 256, 0, stream>>>(act, w2t, b2, z, meta, perm, out);
}

// Round 3
// 171.560 us; speedup vs baseline: 1.1699x; 1.1699x over previous
//
#include <hip/hip_runtime.h>
#include <cstdint>
#include <cstddef>

#define LNUM 8
#define NTOK 8192
#define HDIM 768
#define IDIM 1536

typedef __bf16 bf16x8 __attribute__((ext_vector_type(8)));
typedef float f32x4 __attribute__((ext_vector_type(4)));

__device__ __forceinline__ void gload16(void* lds, const void* gsrc) {
  __builtin_amdgcn_global_load_lds(
      (const __attribute__((address_space(1))) void*)gsrc,
      (__attribute__((address_space(3))) void*)lds, 16, 0, 0);
}

// fast GELU: x * sigmoid(2u), u = 0.79788456*(x + 0.044715 x^3)
// == 0.5x(1+tanh(u)); max abs err vs exact-erf gelu ~3e-3
__device__ __forceinline__ float gelu_f(float x) {
  float xx = x * x;
  float u = x * __builtin_fmaf(0.0356774081f, xx, 0.7978845608f);
  float t = __builtin_exp2f(-2.8853900817779268f * u);  // e^{-2u}
  return x * __builtin_amdgcn_rcpf(1.0f + t);
}

// ---------------- grouping kernels ----------------
// meta ints: [0..7]=counts, [8..15]=cursor, [16..24]=offs, [25..33]=tileOffs128
__global__ void hist_kernel(const int* __restrict__ lid, int* __restrict__ meta) {
  __shared__ int c[LNUM];
  if (threadIdx.x < LNUM) c[threadIdx.x] = 0;
  __syncthreads();
  int i = blockIdx.x * blockDim.x + threadIdx.x;
  atomicAdd(&c[lid[i]], 1);
  __syncthreads();
  if (threadIdx.x < LNUM) atomicAdd(&meta[threadIdx.x], c[threadIdx.x]);
}

__global__ void scan_kernel(int* __restrict__ meta) {
  if (threadIdx.x == 0) {
    int o = 0, t = 0;
    for (int e = 0; e < LNUM; ++e) {
      meta[16 + e] = o;
      meta[25 + e] = t;
      o += meta[e];
      t += (meta[e] + 127) >> 7;
    }
    meta[16 + LNUM] = o;
    meta[25 + LNUM] = t;
  }
}

__global__ void scatter_kernel(const int* __restrict__ lid, int* __restrict__ meta,
                               int* __restrict__ perm) {
  int i = blockIdx.x * blockDim.x + threadIdx.x;
  int e = lid[i];
  int pos = atomicAdd(&meta[8 + e], 1);
  perm[meta[16 + e] + pos] = i;
}

// ---------------- conversion kernels ----------------
__global__ void conv_z_kernel(const float4* __restrict__ z, bf16x8* __restrict__ zb) {
  int i = blockIdx.x * 256 + threadIdx.x;
  float4 a = z[i * 2], b = z[i * 2 + 1];
  bf16x8 o;
  o[0] = (__bf16)a.x; o[1] = (__bf16)a.y; o[2] = (__bf16)a.z; o[3] = (__bf16)a.w;
  o[4] = (__bf16)b.x; o[5] = (__bf16)b.y; o[6] = (__bf16)b.z; o[7] = (__bf16)b.w;
  zb[i] = o;
}

// in: [L][R][C] f32 -> out: [L][C][R] bf16 (transpose + convert), 64x64 tiles
__global__ __launch_bounds__(256) void transpose_cvt_kernel(
    const float* __restrict__ in, __bf16* __restrict__ out, int R, int C) {
  __shared__ float tile[64][65];
  int e = blockIdx.z;
  int c0 = blockIdx.x * 64, r0 = blockIdx.y * 64;
  const float* src = in + (size_t)e * R * C;
  __bf16* dst = out + (size_t)e * R * C;
  int t = threadIdx.x;
  int rr = t >> 4, cc = (t & 15) << 2;
  #pragma unroll
  for (int it = 0; it < 4; ++it) {
    float4 v = *(const float4*)&src[(size_t)(r0 + rr + it * 16) * C + c0 + cc];
    tile[rr + it * 16][cc] = v.x;
    tile[rr + it * 16][cc + 1] = v.y;
    tile[rr + it * 16][cc + 2] = v.z;
    tile[rr + it * 16][cc + 3] = v.w;
  }
  __syncthreads();
  int c = t >> 2, rcb = (t & 3) << 3;
  #pragma unroll
  for (int it = 0; it < 2; ++it) {
    int r = rcb + it * 32;
    bf16x8 o;
    #pragma unroll
    for (int j = 0; j < 8; ++j) o[j] = (__bf16)tile[r + j][c];  // out[c][r+j] = in[r+j][c]
    *(bf16x8*)&dst[(size_t)(c0 + c) * R + r0 + r] = o;
  }
}

// ---------------- grouped GEMM 1: act = gelu(zb[perm] @ w1t^T + b1) ----------------
// LDS rows are 64 elems (128B); content swizzled: Ls[r][c] = G[r][c ^ ((r&7)<<3)]
__global__ __launch_bounds__(256) void gemm1_kernel(
    const __bf16* __restrict__ zb, const __bf16* __restrict__ w1t,
    const float* __restrict__ b1, const int* __restrict__ meta,
    const int* __restrict__ perm, __bf16* __restrict__ act) {
  __shared__ __bf16 As[128 * 64];
  __shared__ __bf16 Bs[128 * 64];
  const int* offs = meta + 16;
  const int* tiles = meta + 25;
  int t = blockIdx.y;
  if (t >= tiles[LNUM]) return;
  int e = 0;
  #pragma unroll
  for (int q = 0; q < LNUM - 1; ++q)
    if (t >= tiles[e + 1]) ++e;
  int mtile = t - tiles[e];
  int row0 = offs[e] + (mtile << 7);
  int cntRem = offs[e + 1] - row0;
  if (cntRem > 128) cntRem = 128;
  int n0 = blockIdx.x << 7;
  int tid = threadIdx.x, lane = tid & 63, wv = tid >> 6;
  int wr = wv >> 1, wc = wv & 1;
  int swz = ((lane & 7) ^ (lane >> 3)) << 3;  // pre-swizzled global elem offset

  const __bf16* srcA[4];
  const __bf16* srcB[4];
  #pragma unroll
  for (int i = 0; i < 4; ++i) {
    int row = ((wv * 4 + i) << 3) + (lane >> 3);
    int rA = row < cntRem ? row : cntRem - 1;
    int tok = perm[row0 + rA];
    srcA[i] = zb + (size_t)tok * HDIM + swz;
    srcB[i] = w1t + ((size_t)e * IDIM + n0 + row) * HDIM + swz;
  }

  int rswz = (lane & 7) << 3;  // read-side XOR (row&7 == lane&7 for frag rows)
  f32x4 acc[4][4] = {};

  for (int kk = 0; kk < HDIM / 64; ++kk) {
    #pragma unroll
    for (int i = 0; i < 4; ++i) {
      gload16((char*)As + ((wv * 4 + i) << 10), srcA[i] + kk * 64);
      gload16((char*)Bs + ((wv * 4 + i) << 10), srcB[i] + kk * 64);
    }
    __syncthreads();
    #pragma unroll
    for (int k2 = 0; k2 < 2; ++k2) {
      int kb = (k2 * 32 + ((lane >> 4) << 3)) ^ rswz;
      bf16x8 a[4], b[4];
      #pragma unroll
      for (int mi = 0; mi < 4; ++mi)
        a[mi] = *(const bf16x8*)&As[((wr * 64 + mi * 16 + (lane & 15)) << 6) + kb];
      #pragma unroll
      for (int ni = 0; ni < 4; ++ni)
        b[ni] = *(const bf16x8*)&Bs[((wc * 64 + ni * 16 + (lane & 15)) << 6) + kb];
      #pragma unroll
      for (int mi = 0; mi < 4; ++mi)
        #pragma unroll
        for (int ni = 0; ni < 4; ++ni)
          acc[mi][ni] = __builtin_amdgcn_mfma_f32_16x16x32_bf16(a[mi], b[ni], acc[mi][ni], 0, 0, 0);
    }
    __syncthreads();
  }

  float bb[4];
  #pragma unroll
  for (int ni = 0; ni < 4; ++ni)
    bb[ni] = b1[e * IDIM + n0 + wc * 64 + ni * 16 + (lane & 15)];

  #pragma unroll
  for (int mi = 0; mi < 4; ++mi) {
    int gr0 = wr * 64 + mi * 16 + ((lane >> 4) << 2);
    #pragma unroll
    for (int r = 0; r < 4; ++r) {
      int g = gr0 + r;
      if (g < cntRem) {
        size_t p = (size_t)(row0 + g);
        #pragma unroll
        for (int ni = 0; ni < 4; ++ni) {
          int col = n0 + wc * 64 + ni * 16 + (lane & 15);
          act[p * IDIM + col] = (__bf16)gelu_f(acc[mi][ni][r] + bb[ni]);
        }
      }
    }
  }
}

// ---------------- grouped GEMM 2: out[tok] = z[tok] + act @ w2t^T + b2 ----------------
__global__ __launch_bounds__(256) void gemm2_kernel(
    const __bf16* __restrict__ act, const __bf16* __restrict__ w2t,
    const float* __restrict__ b2, const float* __restrict__ z,
    const int* __restrict__ meta, const int* __restrict__ perm,
    float* __restrict__ out) {
  __shared__ __bf16 As[128 * 64];
  __shared__ __bf16 Bs[128 * 64];
  const int* offs = meta + 16;
  const int* tiles = meta + 25;
  int t = blockIdx.y;
  if (t >= tiles[LNUM]) return;
  int e = 0;
  #pragma unroll
  for (int q = 0; q < LNUM - 1; ++q)
    if (t >= tiles[e + 1]) ++e;
  int mtile = t - tiles[e];
  int row0 = offs[e] + (mtile << 7);
  int cntRem = offs[e + 1] - row0;
  if (cntRem > 128) cntRem = 128;
  int n0 = blockIdx.x << 7;
  int tid = threadIdx.x, lane = tid & 63, wv = tid >> 6;
  int wr = wv >> 1, wc = wv & 1;
  int swz = ((lane & 7) ^ (lane >> 3)) << 3;

  const __bf16* srcA[4];
  const __bf16* srcB[4];
  #pragma unroll
  for (int i = 0; i < 4; ++i) {
    int row = ((wv * 4 + i) << 3) + (lane >> 3);
    int rA = row < cntRem ? row : cntRem - 1;
    srcA[i] = act + (size_t)(row0 + rA) * IDIM + swz;
    srcB[i] = w2t + ((size_t)e * HDIM + n0 + row) * IDIM + swz;
  }

  int rswz = (lane & 7) << 3;
  f32x4 acc[4][4] = {};

  for (int kk = 0; kk < IDIM / 64; ++kk) {
    #pragma unroll
    for (int i = 0; i < 4; ++i) {
      gload16((char*)As + ((wv * 4 + i) << 10), srcA[i] + kk * 64);
      gload16((char*)Bs + ((wv * 4 + i) << 10), srcB[i] + kk * 64);
    }
    __syncthreads();
    #pragma unroll
    for (int k2 = 0; k2 < 2; ++k2) {
      int kb = (k2 * 32 + ((lane >> 4) << 3)) ^ rswz;
      bf16x8 a[4], b[4];
      #pragma unroll
      for (int mi = 0; mi < 4; ++mi)
        a[mi] = *(const bf16x8*)&As[((wr * 64 + mi * 16 + (lane & 15)) << 6) + kb];
      #pragma unroll
      for (int ni = 0; ni < 4; ++ni)
        b[ni] = *(const bf16x8*)&Bs[((wc * 64 + ni * 16 + (lane & 15)) << 6) + kb];
      #pragma unroll
      for (int mi = 0; mi < 4; ++mi)
        #pragma unroll
        for (int ni = 0; ni < 4; ++ni)
          acc[mi][ni] = __builtin_amdgcn_mfma_f32_16x16x32_bf16(a[mi], b[ni], acc[mi][ni], 0, 0, 0);
    }
    __syncthreads();
  }

  float bb[4];
  #pragma unroll
  for (int ni = 0; ni < 4; ++ni)
    bb[ni] = b2[e * HDIM + n0 + wc * 64 + ni * 16 + (lane & 15)];

  #pragma unroll
  for (int mi = 0; mi < 4; ++mi) {
    int gr0 = wr * 64 + mi * 16 + ((lane >> 4) << 2);
    #pragma unroll
    for (int r = 0; r < 4; ++r) {
      int g = gr0 + r;
      if (g < cntRem) {
        int p = row0 + g;
        int tok = perm[p];
        #pragma unroll
        for (int ni = 0; ni < 4; ++ni) {
          int col = n0 + wc * 64 + ni * 16 + (lane & 15);
          out[(size_t)tok * HDIM + col] =
              z[(size_t)tok * HDIM + col] + acc[mi][ni][r] + bb[ni];
        }
      }
    }
  }
}

extern "C" void kernel_launch(void* const* d_in, const int* in_sizes, int n_in,
                              void* d_out, int out_size, void* d_ws, size_t ws_size,
                              hipStream_t stream) {
  const float* z  = (const float*)d_in[0];
  const int*   lid = (const int*)d_in[1];
  const float* w1 = (const float*)d_in[2];
  const float* b1 = (const float*)d_in[3];
  const float* w2 = (const float*)d_in[4];
  const float* b2 = (const float*)d_in[5];
  float* out = (float*)d_out;
  char* ws = (char*)d_ws;

  int* meta = (int*)ws;             // 34 ints
  int* perm = (int*)(ws + 256);     // NTOK ints
  __bf16* zb  = (__bf16*)(ws + 33280);
  __bf16* w1t = zb + (size_t)NTOK * HDIM;
  __bf16* w2t = w1t + (size_t)LNUM * HDIM * IDIM;
  __bf16* act = w2t + (size_t)LNUM * HDIM * IDIM;

  hipMemsetAsync(meta, 0, 64, stream);
  hist_kernel<<<NTOK / 256, 256, 0, stream>>>(lid, meta);
  scan_kernel<<<1, 64, 0, stream>>>(meta);
  scatter_kernel<<<NTOK / 256, 256, 0, stream>>>(lid, meta, perm);
  conv_z_kernel<<<(NTOK * HDIM / 8) / 256, 256, 0, stream>>>((const float4*)z, (bf16x8*)zb);
  transpose_cvt_kernel<<<dim3(IDIM / 64, HDIM / 64, LNUM), 256, 0, stream>>>(w1, w1t, HDIM, IDIM);
  transpose_cvt_kernel<<<dim3(HDIM / 64, IDIM / 64, LNUM), 256, 0, stream>>>(w2, w2t, IDIM, HDIM);
  gemm1_kernel<<<dim3(IDIM / 128, 72), 256, 0, stream>>>(zb, w1t, b1, meta, perm, act);
  gemm2_kernel<<<dim3(HDIM / 128, 72), 256, 0, stream>>>(act, w2t, b2, z, meta, perm, out);
}

// Round 4
// 167.981 us; speedup vs baseline: 1.1948x; 1.0213x over previous
//
#include <hip/hip_runtime.h>
#include <cstdint>
#include <cstddef>

#define LNUM 8
#define NTOK 8192
#define HDIM 768
#define IDIM 1536

typedef __bf16 bf16x8 __attribute__((ext_vector_type(8)));
typedef float f32x4 __attribute__((ext_vector_type(4)));

__device__ __forceinline__ void gload16(void* lds, const void* gsrc) {
  __builtin_amdgcn_global_load_lds(
      (const __attribute__((address_space(1))) void*)gsrc,
      (__attribute__((address_space(3))) void*)lds, 16, 0, 0);
}

// fast GELU: x * sigmoid(2u), u = 0.79788456*(x + 0.044715 x^3)
__device__ __forceinline__ float gelu_f(float x) {
  float xx = x * x;
  float u = x * __builtin_fmaf(0.0356774081f, xx, 0.7978845608f);
  float t = __builtin_exp2f(-2.8853900817779268f * u);  // e^{-2u}
  return x * __builtin_amdgcn_rcpf(1.0f + t);
}

// ---------------- grouping kernels ----------------
// meta ints: [0..7]=counts, [8..15]=cursor, [16..24]=offs, [25..33]=tileOffs128
__global__ void hist_kernel(const int* __restrict__ lid, int* __restrict__ meta) {
  __shared__ int c[LNUM];
  if (threadIdx.x < LNUM) c[threadIdx.x] = 0;
  __syncthreads();
  int i = blockIdx.x * blockDim.x + threadIdx.x;
  atomicAdd(&c[lid[i]], 1);
  __syncthreads();
  if (threadIdx.x < LNUM) atomicAdd(&meta[threadIdx.x], c[threadIdx.x]);
}

__global__ void scan_kernel(int* __restrict__ meta) {
  if (threadIdx.x == 0) {
    int o = 0, t = 0;
    for (int e = 0; e < LNUM; ++e) {
      meta[16 + e] = o;
      meta[25 + e] = t;
      o += meta[e];
      t += (meta[e] + 127) >> 7;
    }
    meta[16 + LNUM] = o;
    meta[25 + LNUM] = t;
  }
}

__global__ void scatter_kernel(const int* __restrict__ lid, int* __restrict__ meta,
                               int* __restrict__ perm) {
  int i = blockIdx.x * blockDim.x + threadIdx.x;
  int e = lid[i];
  int pos = atomicAdd(&meta[8 + e], 1);
  perm[meta[16 + e] + pos] = i;
}

// ---------------- conversion kernels ----------------
__global__ void conv_z_kernel(const float4* __restrict__ z, bf16x8* __restrict__ zb) {
  int i = blockIdx.x * 256 + threadIdx.x;
  float4 a = z[i * 2], b = z[i * 2 + 1];
  bf16x8 o;
  o[0] = (__bf16)a.x; o[1] = (__bf16)a.y; o[2] = (__bf16)a.z; o[3] = (__bf16)a.w;
  o[4] = (__bf16)b.x; o[5] = (__bf16)b.y; o[6] = (__bf16)b.z; o[7] = (__bf16)b.w;
  zb[i] = o;
}

// in: [L][R][C] f32 -> out: [L][C][R] bf16 (transpose + convert), 64x64 tiles
__global__ __launch_bounds__(256) void transpose_cvt_kernel(
    const float* __restrict__ in, __bf16* __restrict__ out, int R, int C) {
  __shared__ float tile[64][65];
  int e = blockIdx.z;
  int c0 = blockIdx.x * 64, r0 = blockIdx.y * 64;
  const float* src = in + (size_t)e * R * C;
  __bf16* dst = out + (size_t)e * R * C;
  int t = threadIdx.x;
  int rr = t >> 4, cc = (t & 15) << 2;
  #pragma unroll
  for (int it = 0; it < 4; ++it) {
    float4 v = *(const float4*)&src[(size_t)(r0 + rr + it * 16) * C + c0 + cc];
    tile[rr + it * 16][cc] = v.x;
    tile[rr + it * 16][cc + 1] = v.y;
    tile[rr + it * 16][cc + 2] = v.z;
    tile[rr + it * 16][cc + 3] = v.w;
  }
  __syncthreads();
  int c = t >> 2, rcb = (t & 3) << 3;
  #pragma unroll
  for (int it = 0; it < 2; ++it) {
    int r = rcb + it * 32;
    bf16x8 o;
    #pragma unroll
    for (int j = 0; j < 8; ++j) o[j] = (__bf16)tile[r + j][c];
    *(bf16x8*)&dst[(size_t)(c0 + c) * R + r0 + r] = o;
  }
}

// ---------------- grouped GEMM 1: act = gelu(zb[perm] @ w1t^T + b1) ----------------
// 1-D grid (864), XCD-chunk swizzled; LDS double-buffered 2-phase prefetch.
// LDS rows 64 elems; content swizzled: Ls[r][c] = G[r][c ^ ((r&7)<<3)]
__global__ __launch_bounds__(256) void gemm1_kernel(
    const __bf16* __restrict__ zb, const __bf16* __restrict__ w1t,
    const float* __restrict__ b1, const int* __restrict__ meta,
    const int* __restrict__ perm, __bf16* __restrict__ act) {
  __shared__ __bf16 As[2][128 * 64];
  __shared__ __bf16 Bs[2][128 * 64];
  const int* offs = meta + 16;
  const int* tiles = meta + 25;
  int nwg = gridDim.x;
  int bid = blockIdx.x;
  int tileid = (bid & 7) * (nwg >> 3) + (bid >> 3);  // XCD chunking (nwg%8==0)
  int bx = tileid % (IDIM / 128);
  int t = tileid / (IDIM / 128);
  if (t >= tiles[LNUM]) return;
  int e = 0;
  #pragma unroll
  for (int q = 0; q < LNUM - 1; ++q)
    if (t >= tiles[e + 1]) ++e;
  int mtile = t - tiles[e];
  int row0 = offs[e] + (mtile << 7);
  int cntRem = offs[e + 1] - row0;
  if (cntRem > 128) cntRem = 128;
  int n0 = bx << 7;
  int tid = threadIdx.x, lane = tid & 63, wv = tid >> 6;
  int wr = wv >> 1, wc = wv & 1;
  int swz = ((lane & 7) ^ (lane >> 3)) << 3;  // pre-swizzled global elem offset

  const __bf16* srcA[4];
  const __bf16* srcB[4];
  #pragma unroll
  for (int i = 0; i < 4; ++i) {
    int row = ((wv * 4 + i) << 3) + (lane >> 3);
    int rA = row < cntRem ? row : cntRem - 1;
    int tok = perm[row0 + rA];
    srcA[i] = zb + (size_t)tok * HDIM + swz;
    srcB[i] = w1t + ((size_t)e * IDIM + n0 + row) * HDIM + swz;
  }

  int rswz = (lane & 7) << 3;
  f32x4 acc[4][4] = {};

  // prologue stage k-tile 0
  #pragma unroll
  for (int i = 0; i < 4; ++i) {
    gload16((char*)As[0] + ((wv * 4 + i) << 10), srcA[i]);
    gload16((char*)Bs[0] + ((wv * 4 + i) << 10), srcB[i]);
  }
  __syncthreads();

  int cur = 0;
  for (int kk = 0; kk < HDIM / 64; ++kk) {
    if (kk + 1 < HDIM / 64) {
      #pragma unroll
      for (int i = 0; i < 4; ++i) {
        gload16((char*)As[cur ^ 1] + ((wv * 4 + i) << 10), srcA[i] + (kk + 1) * 64);
        gload16((char*)Bs[cur ^ 1] + ((wv * 4 + i) << 10), srcB[i] + (kk + 1) * 64);
      }
    }
    #pragma unroll
    for (int k2 = 0; k2 < 2; ++k2) {
      int kb = (k2 * 32 + ((lane >> 4) << 3)) ^ rswz;
      bf16x8 a[4], b[4];
      #pragma unroll
      for (int mi = 0; mi < 4; ++mi)
        a[mi] = *(const bf16x8*)&As[cur][((wr * 64 + mi * 16 + (lane & 15)) << 6) + kb];
      #pragma unroll
      for (int ni = 0; ni < 4; ++ni)
        b[ni] = *(const bf16x8*)&Bs[cur][((wc * 64 + ni * 16 + (lane & 15)) << 6) + kb];
      #pragma unroll
      for (int mi = 0; mi < 4; ++mi)
        #pragma unroll
        for (int ni = 0; ni < 4; ++ni)
          acc[mi][ni] = __builtin_amdgcn_mfma_f32_16x16x32_bf16(a[mi], b[ni], acc[mi][ni], 0, 0, 0);
    }
    __syncthreads();  // drains this iter's prefetch (vmcnt0) + lds reads
    cur ^= 1;
  }

  float bb[4];
  #pragma unroll
  for (int ni = 0; ni < 4; ++ni)
    bb[ni] = b1[e * IDIM + n0 + wc * 64 + ni * 16 + (lane & 15)];

  #pragma unroll
  for (int mi = 0; mi < 4; ++mi) {
    int gr0 = wr * 64 + mi * 16 + ((lane >> 4) << 2);
    #pragma unroll
    for (int r = 0; r < 4; ++r) {
      int g = gr0 + r;
      if (g < cntRem) {
        size_t p = (size_t)(row0 + g);
        #pragma unroll
        for (int ni = 0; ni < 4; ++ni) {
          int col = n0 + wc * 64 + ni * 16 + (lane & 15);
          act[p * IDIM + col] = (__bf16)gelu_f(acc[mi][ni][r] + bb[ni]);
        }
      }
    }
  }
}

// ---------------- grouped GEMM 2: out[tok] = z[tok] + act @ w2t^T + b2 ----------------
__global__ __launch_bounds__(256) void gemm2_kernel(
    const __bf16* __restrict__ act, const __bf16* __restrict__ w2t,
    const float* __restrict__ b2, const float* __restrict__ z,
    const int* __restrict__ meta, const int* __restrict__ perm,
    float* __restrict__ out) {
  __shared__ __bf16 As[2][128 * 64];
  __shared__ __bf16 Bs[2][128 * 64];
  const int* offs = meta + 16;
  const int* tiles = meta + 25;
  int nwg = gridDim.x;
  int bid = blockIdx.x;
  int tileid = (bid & 7) * (nwg >> 3) + (bid >> 3);
  int bx = tileid % (HDIM / 128);
  int t = tileid / (HDIM / 128);
  if (t >= tiles[LNUM]) return;
  int e = 0;
  #pragma unroll
  for (int q = 0; q < LNUM - 1; ++q)
    if (t >= tiles[e + 1]) ++e;
  int mtile = t - tiles[e];
  int row0 = offs[e] + (mtile << 7);
  int cntRem = offs[e + 1] - row0;
  if (cntRem > 128) cntRem = 128;
  int n0 = bx << 7;
  int tid = threadIdx.x, lane = tid & 63, wv = tid >> 6;
  int wr = wv >> 1, wc = wv & 1;
  int swz = ((lane & 7) ^ (lane >> 3)) << 3;

  const __bf16* srcA[4];
  const __bf16* srcB[4];
  #pragma unroll
  for (int i = 0; i < 4; ++i) {
    int row = ((wv * 4 + i) << 3) + (lane >> 3);
    int rA = row < cntRem ? row : cntRem - 1;
    srcA[i] = act + (size_t)(row0 + rA) * IDIM + swz;
    srcB[i] = w2t + ((size_t)e * HDIM + n0 + row) * IDIM + swz;
  }

  int rswz = (lane & 7) << 3;
  f32x4 acc[4][4] = {};

  #pragma unroll
  for (int i = 0; i < 4; ++i) {
    gload16((char*)As[0] + ((wv * 4 + i) << 10), srcA[i]);
    gload16((char*)Bs[0] + ((wv * 4 + i) << 10), srcB[i]);
  }
  __syncthreads();

  int cur = 0;
  for (int kk = 0; kk < IDIM / 64; ++kk) {
    if (kk + 1 < IDIM / 64) {
      #pragma unroll
      for (int i = 0; i < 4; ++i) {
        gload16((char*)As[cur ^ 1] + ((wv * 4 + i) << 10), srcA[i] + (kk + 1) * 64);
        gload16((char*)Bs[cur ^ 1] + ((wv * 4 + i) << 10), srcB[i] + (kk + 1) * 64);
      }
    }
    #pragma unroll
    for (int k2 = 0; k2 < 2; ++k2) {
      int kb = (k2 * 32 + ((lane >> 4) << 3)) ^ rswz;
      bf16x8 a[4], b[4];
      #pragma unroll
      for (int mi = 0; mi < 4; ++mi)
        a[mi] = *(const bf16x8*)&As[cur][((wr * 64 + mi * 16 + (lane & 15)) << 6) + kb];
      #pragma unroll
      for (int ni = 0; ni < 4; ++ni)
        b[ni] = *(const bf16x8*)&Bs[cur][((wc * 64 + ni * 16 + (lane & 15)) << 6) + kb];
      #pragma unroll
      for (int mi = 0; mi < 4; ++mi)
        #pragma unroll
        for (int ni = 0; ni < 4; ++ni)
          acc[mi][ni] = __builtin_amdgcn_mfma_f32_16x16x32_bf16(a[mi], b[ni], acc[mi][ni], 0, 0, 0);
    }
    __syncthreads();
    cur ^= 1;
  }

  float bb[4];
  #pragma unroll
  for (int ni = 0; ni < 4; ++ni)
    bb[ni] = b2[e * HDIM + n0 + wc * 64 + ni * 16 + (lane & 15)];

  #pragma unroll
  for (int mi = 0; mi < 4; ++mi) {
    int gr0 = wr * 64 + mi * 16 + ((lane >> 4) << 2);
    #pragma unroll
    for (int r = 0; r < 4; ++r) {
      int g = gr0 + r;
      if (g < cntRem) {
        int p = row0 + g;
        int tok = perm[p];
        #pragma unroll
        for (int ni = 0; ni < 4; ++ni) {
          int col = n0 + wc * 64 + ni * 16 + (lane & 15);
          out[(size_t)tok * HDIM + col] =
              z[(size_t)tok * HDIM + col] + acc[mi][ni][r] + bb[ni];
        }
      }
    }
  }
}

extern "C" void kernel_launch(void* const* d_in, const int* in_sizes, int n_in,
                              void* d_out, int out_size, void* d_ws, size_t ws_size,
                              hipStream_t stream) {
  const float* z  = (const float*)d_in[0];
  const int*   lid = (const int*)d_in[1];
  const float* w1 = (const float*)d_in[2];
  const float* b1 = (const float*)d_in[3];
  const float* w2 = (const float*)d_in[4];
  const float* b2 = (const float*)d_in[5];
  float* out = (float*)d_out;
  char* ws = (char*)d_ws;

  int* meta = (int*)ws;             // 34 ints
  int* perm = (int*)(ws + 256);     // NTOK ints
  __bf16* zb  = (__bf16*)(ws + 33280);
  __bf16* w1t = zb + (size_t)NTOK * HDIM;
  __bf16* w2t = w1t + (size_t)LNUM * HDIM * IDIM;
  __bf16* act = w2t + (size_t)LNUM * HDIM * IDIM;

  hipMemsetAsync(meta, 0, 64, stream);
  hist_kernel<<<NTOK / 256, 256, 0, stream>>>(lid, meta);
  scan_kernel<<<1, 64, 0, stream>>>(meta);
  scatter_kernel<<<NTOK / 256, 256, 0, stream>>>(lid, meta, perm);
  conv_z_kernel<<<(NTOK * HDIM / 8) / 256, 256, 0, stream>>>((const float4*)z, (bf16x8*)zb);
  transpose_cvt_kernel<<<dim3(IDIM / 64, HDIM / 64, LNUM), 256, 0, stream>>>(w1, w1t, HDIM, IDIM);
  transpose_cvt_kernel<<<dim3(HDIM / 64, IDIM / 64, LNUM), 256, 0, stream>>>(w2, w2t, IDIM, HDIM);
  gemm1_kernel<<<(IDIM / 128) * 72, 256, 0, stream>>>(zb, w1t, b1, meta, perm, act);
  gemm2_kernel<<<(HDIM / 128) * 72, 256, 0, stream>>>(act, w2t, b2, z, meta, perm, out);
}